// Round 2
// baseline (377.815 us; speedup 1.0000x reference)
//
#include <hip/hip_runtime.h>

// SetNetwork: per-request MLP (64->256->256) + ragged sum-pool + head.
// B=2048, MAXR=512. bf16 MFMA for the per-request MLP, fp32 head.
// Round 2: tile-parallel decomposition — one block per (batch, 64-row tile),
// partial pooled sums in ws, reduced in the head kernel. Swapped layer-1
// MFMA operands give vectorized (b64) H writes.

typedef __bf16 bf16x8 __attribute__((ext_vector_type(8)));
typedef __bf16 bf16x4 __attribute__((ext_vector_type(4)));
typedef float f32x4 __attribute__((ext_vector_type(4)));

#define MFMA16(a, b, c) __builtin_amdgcn_mfma_f32_16x16x32_bf16((a), (b), (c), 0, 0, 0)

// ---------------------------------------------------------------------------
// K1: convert + transpose weights to bf16.  WinT[256][64] = W_in[64][256]^T,
//     We1T[256][256] = W_e1[256][256]^T.  Grid: 320 blocks x 256 threads.
// ---------------------------------------------------------------------------
__global__ __launch_bounds__(256) void convert_w(const float* __restrict__ Win,
                                                 const float* __restrict__ We1,
                                                 __bf16* __restrict__ WinT,
                                                 __bf16* __restrict__ We1T) {
  int t = blockIdx.x * 256 + threadIdx.x;
  if (t < 16384) {
    int nn = t >> 6, k = t & 63;
    WinT[t] = (__bf16)Win[k * 256 + nn];
  } else {
    int e = t - 16384;  // 0..65535
    int nn = e >> 8, k = e & 255;
    We1T[e] = (__bf16)We1[k * 256 + nn];
  }
}

// ---------------------------------------------------------------------------
// K2: one block per (b, t) pair; t = 64-row tile index (0..7).
// 4 waves; wave wid owns hidden-column slice [wid*64, wid*64+64).
// Writes partial pooled sums part[b][t][256] (zeros for empty tiles).
// ---------------------------------------------------------------------------
__global__ __launch_bounds__(256) void mlp_pool(const float* __restrict__ x_req,
                                                const int* __restrict__ n_req,
                                                const __bf16* __restrict__ WinT,
                                                const __bf16* __restrict__ We1T,
                                                float* __restrict__ part) {
  __shared__ __align__(16) __bf16 A[64][72];    // x tile, bf16 (stride 144 B)
  __shared__ __align__(16) __bf16 H[64][264];   // layer-1 out (stride 528 B)

  const int pair = blockIdx.x;
  const int b = pair >> 3, t = pair & 7;
  const int tid = threadIdx.x;
  float* outp = part + (size_t)pair * 256;

  const int n = n_req[b];
  const int valid = n - t * 64;
  if (valid <= 0) {            // empty tile: zero the partial and exit
    outp[tid] = 0.f;
    return;
  }
  const int v = min(64, valid);

  const int wid = tid >> 6;    // wave id 0..3 -> column slice wid*64
  const int lane = tid & 63;
  const int llo = lane & 15;
  const int lhi = lane >> 4;

  // Layer-1 B fragments (W_in^T slice): lane holds WinT[col=n][k..k+8).
  bf16x8 bw1[4][2];
#pragma unroll
  for (int nf = 0; nf < 4; ++nf)
#pragma unroll
    for (int kk = 0; kk < 2; ++kk)
      bw1[nf][kk] = *(const bf16x8*)(WinT + (wid * 64 + nf * 16 + llo) * 64 +
                                     kk * 32 + lhi * 8);

  // ---- stage x_req tile -> A (fp32 -> bf16), zero rows >= v ----
  const float* src = x_req + ((size_t)b * 512 + (size_t)t * 64) * 64;
#pragma unroll
  for (int i = 0; i < 4; ++i) {
    int flat = tid + i * 256;          // float4 id 0..1023
    int row = flat >> 4, c4 = flat & 15;
    float4 w = make_float4(0.f, 0.f, 0.f, 0.f);
    if (row < v) w = ((const float4*)src)[row * 16 + c4];
    bf16x4 hv;
    hv[0] = (__bf16)w.x; hv[1] = (__bf16)w.y;
    hv[2] = (__bf16)w.z; hv[3] = (__bf16)w.w;
    *(bf16x4*)&A[row][c4 * 4] = hv;
  }
  __syncthreads();

  // ---- layer 1 (operands SWAPPED): D[n_local][m] = W^T x ----
  // lane holds n = wid*64+nf*16+lhi*4+r, m = mi*16+llo  -> 4 consecutive
  // hidden cols per lane -> vectorized 8B H writes.
  f32x4 acc1[4][4];
#pragma unroll
  for (int mi = 0; mi < 4; ++mi)
#pragma unroll
    for (int nf = 0; nf < 4; ++nf) acc1[mi][nf] = (f32x4){0.f, 0.f, 0.f, 0.f};
#pragma unroll
  for (int kk = 0; kk < 2; ++kk) {
    bf16x8 af[4];
#pragma unroll
    for (int mi = 0; mi < 4; ++mi)
      af[mi] = *(const bf16x8*)&A[mi * 16 + llo][kk * 32 + lhi * 8];
#pragma unroll
    for (int nf = 0; nf < 4; ++nf)
#pragma unroll
      for (int mi = 0; mi < 4; ++mi)
        acc1[mi][nf] = MFMA16(bw1[nf][kk], af[mi], acc1[mi][nf]);
  }
#pragma unroll
  for (int mi = 0; mi < 4; ++mi)
#pragma unroll
    for (int nf = 0; nf < 4; ++nf) {
      bf16x4 hv;
#pragma unroll
      for (int r = 0; r < 4; ++r) hv[r] = (__bf16)fmaxf(acc1[mi][nf][r], 0.f);
      *(bf16x4*)&H[mi * 16 + llo][wid * 64 + nf * 16 + lhi * 4] = hv;
    }
  __syncthreads();

  // ---- layer 2: [64x256] @ [256x256], relu, accumulate column sums ----
  float colsum[4] = {0.f, 0.f, 0.f, 0.f};  // col = wid*64 + nf*16 + llo
  f32x4 acc2[4][4];
#pragma unroll
  for (int mi = 0; mi < 4; ++mi)
#pragma unroll
    for (int nf = 0; nf < 4; ++nf) acc2[mi][nf] = (f32x4){0.f, 0.f, 0.f, 0.f};
#pragma unroll
  for (int kk = 0; kk < 8; ++kk) {
    bf16x8 af[4];
#pragma unroll
    for (int mi = 0; mi < 4; ++mi)
      af[mi] = *(const bf16x8*)&H[mi * 16 + llo][kk * 32 + lhi * 8];
#pragma unroll
    for (int nf = 0; nf < 4; ++nf) {
      bf16x8 bf_ = *(const bf16x8*)(We1T +
                      (size_t)(wid * 64 + nf * 16 + llo) * 256 +
                      kk * 32 + lhi * 8);
#pragma unroll
      for (int mi = 0; mi < 4; ++mi)
        acc2[mi][nf] = MFMA16(af[mi], bf_, acc2[mi][nf]);
    }
  }
#pragma unroll
  for (int mi = 0; mi < 4; ++mi)
#pragma unroll
    for (int nf = 0; nf < 4; ++nf)
#pragma unroll
      for (int r = 0; r < 4; ++r)
        colsum[nf] += fmaxf(acc2[mi][nf][r], 0.f);

  // reduce column sums across the 4 lane-groups, write partial pooled slice
#pragma unroll
  for (int nf = 0; nf < 4; ++nf) {
    float s = colsum[nf];
    s += __shfl_xor(s, 16);
    s += __shfl_xor(s, 32);
    if (lane < 16) outp[wid * 64 + nf * 16 + lane] = s;
  }
}

// ---------------------------------------------------------------------------
// K3: head.  pooled = sum_t part[b][t]; req_embed = relu(pooled @ W_e2);
//     x = [x_inst, req_embed]; h = relu(x @ W_c + b_c); out = h @ W_o + b_o.
// 16 batch rows per block, 128 blocks x 256 threads, fp32.
// ---------------------------------------------------------------------------
__global__ __launch_bounds__(256) void head_kernel(const float* __restrict__ x_inst,
                                                   const float* __restrict__ part,
                                                   const float* __restrict__ We2,
                                                   const float* __restrict__ Wc,
                                                   const float* __restrict__ bc,
                                                   const float* __restrict__ Wo,
                                                   const float* __restrict__ bo,
                                                   float* __restrict__ out) {
  __shared__ float P[16][256];
  __shared__ float XC[16][192];
  __shared__ float RED[4][16];
  const int tid = threadIdx.x;
  const int r0 = blockIdx.x * 16;

  // stage pooled rows (16x256) = sum of 8 partials; x_inst rows -> XC[:,0:64]
#pragma unroll
  for (int i = 0; i < 4; ++i) {
    int flat = tid + i * 256;
    int row = flat >> 6, c4 = flat & 63;
    float4 s = make_float4(0.f, 0.f, 0.f, 0.f);
#pragma unroll
    for (int tt = 0; tt < 8; ++tt) {
      float4 p = ((const float4*)(part + ((size_t)(r0 + row) * 8 + tt) * 256))[c4];
      s.x += p.x; s.y += p.y; s.z += p.z; s.w += p.w;
    }
    *(float4*)&P[row][c4 * 4] = s;
  }
  {
    int row = tid >> 4, c4 = tid & 15;
    float4 w = ((const float4*)(x_inst + (size_t)(r0 + row) * 64))[c4];
    *(float4*)&XC[row][c4 * 4] = w;
  }
  __syncthreads();

  // req_embed: 128 cols, threads split {row-half rh, col j}
  {
    const int rh = tid >> 7, j = tid & 127;
    float acc[8] = {0.f, 0.f, 0.f, 0.f, 0.f, 0.f, 0.f, 0.f};
    for (int k4 = 0; k4 < 64; ++k4) {
      float w0 = We2[(k4 * 4 + 0) * 128 + j];
      float w1 = We2[(k4 * 4 + 1) * 128 + j];
      float w2 = We2[(k4 * 4 + 2) * 128 + j];
      float w3 = We2[(k4 * 4 + 3) * 128 + j];
#pragma unroll
      for (int rr = 0; rr < 8; ++rr) {
        float4 pv = *(const float4*)&P[rh * 8 + rr][k4 * 4];
        acc[rr] += pv.x * w0 + pv.y * w1 + pv.z * w2 + pv.w * w3;
      }
    }
#pragma unroll
    for (int rr = 0; rr < 8; ++rr)
      XC[rh * 8 + rr][64 + j] = fmaxf(acc[rr], 0.f);
  }
  __syncthreads();

  // hidden (192->512) + output dot, 2 cols per thread
  float part_r[16];
#pragma unroll
  for (int r = 0; r < 16; ++r) part_r[r] = 0.f;
#pragma unroll
  for (int jj = 0; jj < 2; ++jj) {
    const int j = tid + jj * 256;
    float acc[16];
#pragma unroll
    for (int r = 0; r < 16; ++r) acc[r] = 0.f;
    for (int k4 = 0; k4 < 48; ++k4) {
      float w0 = Wc[(k4 * 4 + 0) * 512 + j];
      float w1 = Wc[(k4 * 4 + 1) * 512 + j];
      float w2 = Wc[(k4 * 4 + 2) * 512 + j];
      float w3 = Wc[(k4 * 4 + 3) * 512 + j];
#pragma unroll
      for (int r = 0; r < 16; ++r) {
        float4 xv = *(const float4*)&XC[r][k4 * 4];
        acc[r] += xv.x * w0 + xv.y * w1 + xv.z * w2 + xv.w * w3;
      }
    }
    const float bcv = bc[j], wov = Wo[j];
#pragma unroll
    for (int r = 0; r < 16; ++r)
      part_r[r] += fmaxf(acc[r] + bcv, 0.f) * wov;
  }
  // block reduction of part_r[16] over 256 threads
#pragma unroll
  for (int r = 0; r < 16; ++r) {
    part_r[r] += __shfl_xor(part_r[r], 1);
    part_r[r] += __shfl_xor(part_r[r], 2);
    part_r[r] += __shfl_xor(part_r[r], 4);
    part_r[r] += __shfl_xor(part_r[r], 8);
    part_r[r] += __shfl_xor(part_r[r], 16);
    part_r[r] += __shfl_xor(part_r[r], 32);
  }
  const int wid = tid >> 6, lane = tid & 63;
  if (lane == 0) {
#pragma unroll
    for (int r = 0; r < 16; ++r) RED[wid][r] = part_r[r];
  }
  __syncthreads();
  if (tid < 16)
    out[r0 + tid] = RED[0][tid] + RED[1][tid] + RED[2][tid] + RED[3][tid] + bo[0];
}

// ---------------------------------------------------------------------------
extern "C" void kernel_launch(void* const* d_in, const int* in_sizes, int n_in,
                              void* d_out, int out_size, void* d_ws, size_t ws_size,
                              hipStream_t stream) {
  const float* x_inst = (const float*)d_in[0];
  const float* x_req  = (const float*)d_in[1];
  const int*   n_req  = (const int*)d_in[2];
  const float* W_in   = (const float*)d_in[3];
  const float* W_e1   = (const float*)d_in[4];
  const float* W_e2   = (const float*)d_in[5];
  const float* W_c    = (const float*)d_in[6];
  const float* b_c    = (const float*)d_in[7];
  const float* W_o    = (const float*)d_in[8];
  const float* b_o    = (const float*)d_in[9];
  float* out = (float*)d_out;

  char* ws = (char*)d_ws;
  const size_t PART_BYTES = (size_t)2048 * 8 * 256 * 4;   // 16.78 MB
  float*  partbuf = (float*)ws;
  __bf16* WinT    = (__bf16*)(ws + PART_BYTES);           // 32 KiB
  __bf16* We1T    = (__bf16*)(ws + PART_BYTES + 32 * 1024);  // 128 KiB

  convert_w<<<320, 256, 0, stream>>>(W_in, W_e1, WinT, We1T);
  mlp_pool<<<2048 * 8, 256, 0, stream>>>(x_req, n_req, WinT, We1T, partbuf);
  head_kernel<<<128, 256, 0, stream>>>(x_inst, partbuf, W_e2, W_c, b_c, W_o, b_o, out);
}

// Round 3
// 302.448 us; speedup vs baseline: 1.2492x; 1.2492x over previous
//
#include <hip/hip_runtime.h>

// SetNetwork: per-request MLP (64->256->256) + ragged sum-pool + head.
// Round 3: persistent mlp blocks over a prefix-scanned worklist of non-empty
// (b,t) tiles, double-buffered A with cross-item prefetch, weights hoisted
// per-block. Head sums only the valid tile partials.

typedef __bf16 bf16x8 __attribute__((ext_vector_type(8)));
typedef __bf16 bf16x4 __attribute__((ext_vector_type(4)));
typedef float f32x4 __attribute__((ext_vector_type(4)));

#define MFMA16(a, b, c) __builtin_amdgcn_mfma_f32_16x16x32_bf16((a), (b), (c), 0, 0, 0)

#define G_BLOCKS 768  // 3 blocks/CU x 256 CUs (LDS cap: 52 KB/block)

// ---------------------------------------------------------------------------
// K1 (fused): blocks 0..319 convert+transpose weights to bf16;
//             block 320 prefix-scans n_req into a worklist of (b,t) tiles.
// ---------------------------------------------------------------------------
__global__ __launch_bounds__(256) void prep(const float* __restrict__ Win,
                                            const float* __restrict__ We1,
                                            const int* __restrict__ n_req,
                                            __bf16* __restrict__ WinT,
                                            __bf16* __restrict__ We1T,
                                            unsigned int* __restrict__ worklist,
                                            int* __restrict__ wl_count) {
  if (blockIdx.x < 320) {
    int t = blockIdx.x * 256 + threadIdx.x;
    if (t < 16384) {
      int nn = t >> 6, k = t & 63;
      WinT[t] = (__bf16)Win[k * 256 + nn];       // WinT[256][64]
    } else {
      int e = t - 16384;                          // 0..65535
      int nn = e >> 8, k = e & 255;
      We1T[e] = (__bf16)We1[k * 256 + nn];       // We1T[256][256]
    }
    return;
  }
  // ---- worklist build: 256 threads x 8 batches each ----
  __shared__ int wsum[4];
  const int tid = threadIdx.x;
  const int base = tid * 8;
  int nt[8], s = 0;
#pragma unroll
  for (int j = 0; j < 8; ++j) {
    int n = n_req[base + j];
    nt[j] = (n + 63) >> 6;  // tiles for this batch (0..8)
    s += nt[j];
  }
  const int lane = tid & 63, wv = tid >> 6;
  int inc = s;
#pragma unroll
  for (int d = 1; d < 64; d <<= 1) {
    int u = __shfl_up(inc, d);
    if (lane >= d) inc += u;
  }
  if (lane == 63) wsum[wv] = inc;
  __syncthreads();
  int woff = 0;
  for (int w = 0; w < wv; ++w) woff += wsum[w];
  int off = woff + inc - s;  // exclusive prefix for this thread
#pragma unroll
  for (int j = 0; j < 8; ++j) {
    int b = base + j;
    for (int t = 0; t < nt[j]; ++t) worklist[off++] = (unsigned int)(b * 8 + t);
  }
  if (tid == 255) wl_count[0] = woff + inc;
}

// ---------------------------------------------------------------------------
// K2: persistent blocks; each loops over worklist items i, i+G, ...
// Per item: stage x tile (bf16) -> layer1 MFMA -> H(LDS) -> layer2 MFMA ->
// column-sum -> part[b*8+t][256]. A double-buffered; next item's x_req loads
// issue under the current item's MFMAs.
// ---------------------------------------------------------------------------
__global__ __launch_bounds__(256, 3) void mlp_pool(const float* __restrict__ x_req,
                                                   const int* __restrict__ n_req,
                                                   const __bf16* __restrict__ WinT,
                                                   const __bf16* __restrict__ We1T,
                                                   const unsigned int* __restrict__ worklist,
                                                   const int* __restrict__ wl_count,
                                                   float* __restrict__ part) {
  __shared__ __align__(16) __bf16 A[2][64][72];  // x tiles (stride 144 B)
  __shared__ __align__(16) __bf16 H[64][264];    // layer-1 out (stride 528 B)

  const int tid = threadIdx.x;
  const int wid = tid >> 6;    // wave id 0..3 -> hidden column slice wid*64
  const int lane = tid & 63;
  const int llo = lane & 15;
  const int lhi = lane >> 4;

  const int count = wl_count[0];
  int i = blockIdx.x;
  if (i >= count) return;

  // Layer-1 B fragments (W_in^T slice), loaded once per block.
  bf16x8 bw1[4][2];
#pragma unroll
  for (int nf = 0; nf < 4; ++nf)
#pragma unroll
    for (int kk = 0; kk < 2; ++kk)
      bw1[nf][kk] = *(const bf16x8*)(WinT + (wid * 64 + nf * 16 + llo) * 64 +
                                     kk * 32 + lhi * 8);

  // staging-thread coords: thread handles float4 ids tid, tid+256, ..
  const int srow[4] = {tid >> 4, (tid + 256) >> 4, (tid + 512) >> 4, (tid + 768) >> 4};
  const int sc4 = tid & 15;

  // ---- prologue: stage item i into A[0] ----
  unsigned int cit = worklist[i];
  float4 pf[4];
  {
    int cb = (int)(cit >> 3), ct = (int)(cit & 7);
    int cv = min(64, n_req[cb] - ct * 64);
    const float* src = x_req + ((size_t)cb * 512 + (size_t)ct * 64) * 64;
#pragma unroll
    for (int s = 0; s < 4; ++s)
      pf[s] = (srow[s] < cv) ? ((const float4*)src)[srow[s] * 16 + sc4]
                             : make_float4(0.f, 0.f, 0.f, 0.f);
#pragma unroll
    for (int s = 0; s < 4; ++s) {
      bf16x4 hv;
      hv[0] = (__bf16)pf[s].x; hv[1] = (__bf16)pf[s].y;
      hv[2] = (__bf16)pf[s].z; hv[3] = (__bf16)pf[s].w;
      *(bf16x4*)&A[0][srow[s]][sc4 * 4] = hv;
    }
  }
  int cur = 0;

  for (; i < count; i += G_BLOCKS) {
    const int inext = i + G_BLOCKS;
    const bool hn = inext < count;
    unsigned int nit = hn ? worklist[inext] : 0u;  // issue early

    __syncthreads();  // B1: A[cur] staged; previous item fully consumed

    // ---- layer-1 A fragments from A[cur] ----
    bf16x8 af[2][4];
#pragma unroll
    for (int kk = 0; kk < 2; ++kk)
#pragma unroll
      for (int mi = 0; mi < 4; ++mi)
        af[kk][mi] = *(const bf16x8*)&A[cur][mi * 16 + llo][kk * 32 + lhi * 8];

    // ---- issue next item's x_req loads (hide HBM under MFMAs) ----
    if (hn) {
      int nb = (int)(nit >> 3), ntl = (int)(nit & 7);
      int nv = min(64, n_req[nb] - ntl * 64);
      const float* src = x_req + ((size_t)nb * 512 + (size_t)ntl * 64) * 64;
#pragma unroll
      for (int s = 0; s < 4; ++s)
        pf[s] = (srow[s] < nv) ? ((const float4*)src)[srow[s] * 16 + sc4]
                               : make_float4(0.f, 0.f, 0.f, 0.f);
    }

    // ---- layer 1 (swapped operands): D[n][m], lane holds 4 consecutive n ----
    f32x4 acc1[4][4];
#pragma unroll
    for (int mi = 0; mi < 4; ++mi)
#pragma unroll
      for (int nf = 0; nf < 4; ++nf) acc1[mi][nf] = (f32x4){0.f, 0.f, 0.f, 0.f};
#pragma unroll
    for (int kk = 0; kk < 2; ++kk)
#pragma unroll
      for (int nf = 0; nf < 4; ++nf)
#pragma unroll
        for (int mi = 0; mi < 4; ++mi)
          acc1[mi][nf] = MFMA16(bw1[nf][kk], af[kk][mi], acc1[mi][nf]);
#pragma unroll
    for (int mi = 0; mi < 4; ++mi)
#pragma unroll
      for (int nf = 0; nf < 4; ++nf) {
        bf16x4 hv;
#pragma unroll
        for (int r = 0; r < 4; ++r) hv[r] = (__bf16)fmaxf(acc1[mi][nf][r], 0.f);
        *(bf16x4*)&H[mi * 16 + llo][wid * 64 + nf * 16 + lhi * 4] = hv;
      }
    __syncthreads();  // B2: H ready; A[cur^1] readers (2 barriers ago) done

    // ---- write prefetched next tile into A[cur^1] ----
    if (hn) {
#pragma unroll
      for (int s = 0; s < 4; ++s) {
        bf16x4 hv;
        hv[0] = (__bf16)pf[s].x; hv[1] = (__bf16)pf[s].y;
        hv[2] = (__bf16)pf[s].z; hv[3] = (__bf16)pf[s].w;
        *(bf16x4*)&A[cur ^ 1][srow[s]][sc4 * 4] = hv;
      }
    }

    // ---- layer 2: [64x256] @ [256x256], relu, column sums ----
    f32x4 acc2[4][4];
#pragma unroll
    for (int mi = 0; mi < 4; ++mi)
#pragma unroll
      for (int nf = 0; nf < 4; ++nf) acc2[mi][nf] = (f32x4){0.f, 0.f, 0.f, 0.f};
#pragma unroll
    for (int kk = 0; kk < 8; ++kk) {
      bf16x8 a2[4];
#pragma unroll
      for (int mi = 0; mi < 4; ++mi)
        a2[mi] = *(const bf16x8*)&H[mi * 16 + llo][kk * 32 + lhi * 8];
#pragma unroll
      for (int nf = 0; nf < 4; ++nf) {
        bf16x8 bf_ = *(const bf16x8*)(We1T +
                        (size_t)(wid * 64 + nf * 16 + llo) * 256 +
                        kk * 32 + lhi * 8);
#pragma unroll
        for (int mi = 0; mi < 4; ++mi)
          acc2[mi][nf] = MFMA16(a2[mi], bf_, acc2[mi][nf]);
      }
    }
    float colsum[4];
#pragma unroll
    for (int nf = 0; nf < 4; ++nf) colsum[nf] = 0.f;
#pragma unroll
    for (int mi = 0; mi < 4; ++mi)
#pragma unroll
      for (int nf = 0; nf < 4; ++nf)
#pragma unroll
        for (int r = 0; r < 4; ++r)
          colsum[nf] += fmaxf(acc2[mi][nf][r], 0.f);

    // reduce across lane-groups; write this item's partial pooled slice
    float* outp = part + (size_t)cit * 256;
#pragma unroll
    for (int nf = 0; nf < 4; ++nf) {
      float s = colsum[nf];
      s += __shfl_xor(s, 16);
      s += __shfl_xor(s, 32);
      if (lane < 16) outp[wid * 64 + nf * 16 + lane] = s;
    }

    cit = nit;
    cur ^= 1;
  }
}

// ---------------------------------------------------------------------------
// K3: head.  pooled = sum_{t<ceil(n/64)} part[b*8+t]; req_embed = relu(pooled
// @ W_e2); x = [x_inst, req_embed]; h = relu(x @ W_c + b_c); out = h@W_o+b_o.
// 16 batch rows per block, 128 blocks x 256 threads, fp32.
// ---------------------------------------------------------------------------
__global__ __launch_bounds__(256) void head_kernel(const float* __restrict__ x_inst,
                                                   const float* __restrict__ part,
                                                   const int* __restrict__ n_req,
                                                   const float* __restrict__ We2,
                                                   const float* __restrict__ Wc,
                                                   const float* __restrict__ bc,
                                                   const float* __restrict__ Wo,
                                                   const float* __restrict__ bo,
                                                   float* __restrict__ out) {
  __shared__ float P[16][256];
  __shared__ float XC[16][192];
  __shared__ float RED[4][16];
  const int tid = threadIdx.x;
  const int r0 = blockIdx.x * 16;

  // stage pooled rows (16x256) = sum of valid partials; x_inst -> XC[:,0:64]
#pragma unroll
  for (int i = 0; i < 4; ++i) {
    int flat = tid + i * 256;
    int row = flat >> 6, c4 = flat & 63;
    int ntiles = (n_req[r0 + row] + 63) >> 6;
    float4 s = make_float4(0.f, 0.f, 0.f, 0.f);
    for (int tt = 0; tt < ntiles; ++tt) {
      float4 p = ((const float4*)(part + ((size_t)(r0 + row) * 8 + tt) * 256))[c4];
      s.x += p.x; s.y += p.y; s.z += p.z; s.w += p.w;
    }
    *(float4*)&P[row][c4 * 4] = s;
  }
  {
    int row = tid >> 4, c4 = tid & 15;
    float4 w = ((const float4*)(x_inst + (size_t)(r0 + row) * 64))[c4];
    *(float4*)&XC[row][c4 * 4] = w;
  }
  __syncthreads();

  // req_embed: 128 cols, threads split {row-half rh, col j}
  {
    const int rh = tid >> 7, j = tid & 127;
    float acc[8] = {0.f, 0.f, 0.f, 0.f, 0.f, 0.f, 0.f, 0.f};
    for (int k4 = 0; k4 < 64; ++k4) {
      float w0 = We2[(k4 * 4 + 0) * 128 + j];
      float w1 = We2[(k4 * 4 + 1) * 128 + j];
      float w2 = We2[(k4 * 4 + 2) * 128 + j];
      float w3 = We2[(k4 * 4 + 3) * 128 + j];
#pragma unroll
      for (int rr = 0; rr < 8; ++rr) {
        float4 pv = *(const float4*)&P[rh * 8 + rr][k4 * 4];
        acc[rr] += pv.x * w0 + pv.y * w1 + pv.z * w2 + pv.w * w3;
      }
    }
#pragma unroll
    for (int rr = 0; rr < 8; ++rr)
      XC[rh * 8 + rr][64 + j] = fmaxf(acc[rr], 0.f);
  }
  __syncthreads();

  // hidden (192->512) + output dot, 2 cols per thread
  float part_r[16];
#pragma unroll
  for (int r = 0; r < 16; ++r) part_r[r] = 0.f;
#pragma unroll
  for (int jj = 0; jj < 2; ++jj) {
    const int j = tid + jj * 256;
    float acc[16];
#pragma unroll
    for (int r = 0; r < 16; ++r) acc[r] = 0.f;
    for (int k4 = 0; k4 < 48; ++k4) {
      float w0 = Wc[(k4 * 4 + 0) * 512 + j];
      float w1 = Wc[(k4 * 4 + 1) * 512 + j];
      float w2 = Wc[(k4 * 4 + 2) * 512 + j];
      float w3 = Wc[(k4 * 4 + 3) * 512 + j];
#pragma unroll
      for (int r = 0; r < 16; ++r) {
        float4 xv = *(const float4*)&XC[r][k4 * 4];
        acc[r] += xv.x * w0 + xv.y * w1 + xv.z * w2 + xv.w * w3;
      }
    }
    const float bcv = bc[j], wov = Wo[j];
#pragma unroll
    for (int r = 0; r < 16; ++r)
      part_r[r] += fmaxf(acc[r] + bcv, 0.f) * wov;
  }
  // block reduction of part_r[16] over 256 threads
#pragma unroll
  for (int r = 0; r < 16; ++r) {
    part_r[r] += __shfl_xor(part_r[r], 1);
    part_r[r] += __shfl_xor(part_r[r], 2);
    part_r[r] += __shfl_xor(part_r[r], 4);
    part_r[r] += __shfl_xor(part_r[r], 8);
    part_r[r] += __shfl_xor(part_r[r], 16);
    part_r[r] += __shfl_xor(part_r[r], 32);
  }
  const int wv = tid >> 6, lane = tid & 63;
  if (lane == 0) {
#pragma unroll
    for (int r = 0; r < 16; ++r) RED[wv][r] = part_r[r];
  }
  __syncthreads();
  if (tid < 16)
    out[r0 + tid] = RED[0][tid] + RED[1][tid] + RED[2][tid] + RED[3][tid] + bo[0];
}

// ---------------------------------------------------------------------------
extern "C" void kernel_launch(void* const* d_in, const int* in_sizes, int n_in,
                              void* d_out, int out_size, void* d_ws, size_t ws_size,
                              hipStream_t stream) {
  const float* x_inst = (const float*)d_in[0];
  const float* x_req  = (const float*)d_in[1];
  const int*   n_req  = (const int*)d_in[2];
  const float* W_in   = (const float*)d_in[3];
  const float* W_e1   = (const float*)d_in[4];
  const float* W_e2   = (const float*)d_in[5];
  const float* W_c    = (const float*)d_in[6];
  const float* b_c    = (const float*)d_in[7];
  const float* W_o    = (const float*)d_in[8];
  const float* b_o    = (const float*)d_in[9];
  float* out = (float*)d_out;

  char* ws = (char*)d_ws;
  const size_t PART_BYTES = (size_t)2048 * 8 * 256 * 4;        // 16.78 MB
  float*        partbuf  = (float*)ws;
  __bf16*       WinT     = (__bf16*)(ws + PART_BYTES);         // 32 KiB
  __bf16*       We1T     = (__bf16*)(ws + PART_BYTES + (32 << 10));   // 128 KiB
  unsigned int* worklist = (unsigned int*)(ws + PART_BYTES + (160 << 10));  // 64 KiB
  int*          wl_count = (int*)(ws + PART_BYTES + (224 << 10));

  prep<<<321, 256, 0, stream>>>(W_in, W_e1, n_req, WinT, We1T, worklist, wl_count);
  mlp_pool<<<G_BLOCKS, 256, 0, stream>>>(x_req, n_req, WinT, We1T, worklist,
                                         wl_count, partbuf);
  head_kernel<<<128, 256, 0, stream>>>(x_inst, partbuf, n_req, W_e2, W_c, b_c,
                                       W_o, b_o, out);
}

// Round 4
// 216.024 us; speedup vs baseline: 1.7489x; 1.4001x over previous
//
#include <hip/hip_runtime.h>

// SetNetwork: per-request MLP (64->256->256) + ragged sum-pool + head.
// Round 4: identical structure to R3 (persistent worklist, double-buffered A,
// cross-item prefetch) with the spill fixed: __launch_bounds__(256,2) lifts
// the unified VGPR cap 168 -> 256 (R3's cap split 84 arch + 84 acc and
// spilled the loop-carried prefetch: WRITE_SIZE 186 MB). Grid 512 = exact
// residency (2 blocks/CU).

typedef __bf16 bf16x8 __attribute__((ext_vector_type(8)));
typedef __bf16 bf16x4 __attribute__((ext_vector_type(4)));
typedef float f32x4 __attribute__((ext_vector_type(4)));

#define MFMA16(a, b, c) __builtin_amdgcn_mfma_f32_16x16x32_bf16((a), (b), (c), 0, 0, 0)

#define G_BLOCKS 512  // 2 blocks/CU x 256 CUs (VGPR cap 256 -> 2 resident)

// ---------------------------------------------------------------------------
// K1 (fused): blocks 0..319 convert+transpose weights to bf16;
//             block 320 prefix-scans n_req into a worklist of (b,t) tiles.
// ---------------------------------------------------------------------------
__global__ __launch_bounds__(256) void prep(const float* __restrict__ Win,
                                            const float* __restrict__ We1,
                                            const int* __restrict__ n_req,
                                            __bf16* __restrict__ WinT,
                                            __bf16* __restrict__ We1T,
                                            unsigned int* __restrict__ worklist,
                                            int* __restrict__ wl_count) {
  if (blockIdx.x < 320) {
    int t = blockIdx.x * 256 + threadIdx.x;
    if (t < 16384) {
      int nn = t >> 6, k = t & 63;
      WinT[t] = (__bf16)Win[k * 256 + nn];       // WinT[256][64]
    } else {
      int e = t - 16384;                          // 0..65535
      int nn = e >> 8, k = e & 255;
      We1T[e] = (__bf16)We1[k * 256 + nn];       // We1T[256][256]
    }
    return;
  }
  // ---- worklist build: 256 threads x 8 batches each ----
  __shared__ int wsum[4];
  const int tid = threadIdx.x;
  const int base = tid * 8;
  int nt[8], s = 0;
#pragma unroll
  for (int j = 0; j < 8; ++j) {
    int n = n_req[base + j];
    nt[j] = (n + 63) >> 6;  // tiles for this batch (0..8)
    s += nt[j];
  }
  const int lane = tid & 63, wv = tid >> 6;
  int inc = s;
#pragma unroll
  for (int d = 1; d < 64; d <<= 1) {
    int u = __shfl_up(inc, d);
    if (lane >= d) inc += u;
  }
  if (lane == 63) wsum[wv] = inc;
  __syncthreads();
  int woff = 0;
  for (int w = 0; w < wv; ++w) woff += wsum[w];
  int off = woff + inc - s;  // exclusive prefix for this thread
#pragma unroll
  for (int j = 0; j < 8; ++j) {
    int b = base + j;
    for (int t = 0; t < nt[j]; ++t) worklist[off++] = (unsigned int)(b * 8 + t);
  }
  if (tid == 255) wl_count[0] = woff + inc;
}

// ---------------------------------------------------------------------------
// K2: persistent blocks; each loops over worklist items i, i+G, ...
// Per item: stage x tile (bf16) -> layer1 MFMA -> H(LDS) -> layer2 MFMA ->
// column-sum -> part[b*8+t][256]. A double-buffered; next item's x_req loads
// issue under the current item's MFMAs.
// ---------------------------------------------------------------------------
__global__ __launch_bounds__(256, 2) void mlp_pool(const float* __restrict__ x_req,
                                                   const int* __restrict__ n_req,
                                                   const __bf16* __restrict__ WinT,
                                                   const __bf16* __restrict__ We1T,
                                                   const unsigned int* __restrict__ worklist,
                                                   const int* __restrict__ wl_count,
                                                   float* __restrict__ part) {
  __shared__ __align__(16) __bf16 A[2][64][72];  // x tiles (stride 144 B)
  __shared__ __align__(16) __bf16 H[64][264];    // layer-1 out (stride 528 B)

  const int tid = threadIdx.x;
  const int wid = tid >> 6;    // wave id 0..3 -> hidden column slice wid*64
  const int lane = tid & 63;
  const int llo = lane & 15;
  const int lhi = lane >> 4;

  const int count = wl_count[0];
  int i = blockIdx.x;
  if (i >= count) return;

  // Layer-1 B fragments (W_in^T slice), loaded once per block.
  bf16x8 bw1[4][2];
#pragma unroll
  for (int nf = 0; nf < 4; ++nf)
#pragma unroll
    for (int kk = 0; kk < 2; ++kk)
      bw1[nf][kk] = *(const bf16x8*)(WinT + (wid * 64 + nf * 16 + llo) * 64 +
                                     kk * 32 + lhi * 8);

  // staging-thread coords: thread handles float4 ids tid, tid+256, ..
  const int srow[4] = {tid >> 4, (tid + 256) >> 4, (tid + 512) >> 4, (tid + 768) >> 4};
  const int sc4 = tid & 15;

  // ---- prologue: stage item i into A[0] ----
  unsigned int cit = worklist[i];
  float4 pf[4];
  {
    int cb = (int)(cit >> 3), ct = (int)(cit & 7);
    int cv = min(64, n_req[cb] - ct * 64);
    const float* src = x_req + ((size_t)cb * 512 + (size_t)ct * 64) * 64;
#pragma unroll
    for (int s = 0; s < 4; ++s)
      pf[s] = (srow[s] < cv) ? ((const float4*)src)[srow[s] * 16 + sc4]
                             : make_float4(0.f, 0.f, 0.f, 0.f);
#pragma unroll
    for (int s = 0; s < 4; ++s) {
      bf16x4 hv;
      hv[0] = (__bf16)pf[s].x; hv[1] = (__bf16)pf[s].y;
      hv[2] = (__bf16)pf[s].z; hv[3] = (__bf16)pf[s].w;
      *(bf16x4*)&A[0][srow[s]][sc4 * 4] = hv;
    }
  }
  int cur = 0;

  for (; i < count; i += G_BLOCKS) {
    const int inext = i + G_BLOCKS;
    const bool hn = inext < count;
    unsigned int nit = hn ? worklist[inext] : 0u;  // issue early

    __syncthreads();  // B1: A[cur] staged; previous item fully consumed

    // ---- layer-1 A fragments from A[cur] ----
    bf16x8 af[2][4];
#pragma unroll
    for (int kk = 0; kk < 2; ++kk)
#pragma unroll
      for (int mi = 0; mi < 4; ++mi)
        af[kk][mi] = *(const bf16x8*)&A[cur][mi * 16 + llo][kk * 32 + lhi * 8];

    // ---- issue next item's x_req loads (hide HBM under MFMAs) ----
    if (hn) {
      int nb = (int)(nit >> 3), ntl = (int)(nit & 7);
      int nv = min(64, n_req[nb] - ntl * 64);
      const float* src = x_req + ((size_t)nb * 512 + (size_t)ntl * 64) * 64;
#pragma unroll
      for (int s = 0; s < 4; ++s)
        pf[s] = (srow[s] < nv) ? ((const float4*)src)[srow[s] * 16 + sc4]
                               : make_float4(0.f, 0.f, 0.f, 0.f);
    }

    // ---- layer 1 (swapped operands): D[n][m], lane holds 4 consecutive n ----
    f32x4 acc1[4][4];
#pragma unroll
    for (int mi = 0; mi < 4; ++mi)
#pragma unroll
      for (int nf = 0; nf < 4; ++nf) acc1[mi][nf] = (f32x4){0.f, 0.f, 0.f, 0.f};
#pragma unroll
    for (int kk = 0; kk < 2; ++kk)
#pragma unroll
      for (int nf = 0; nf < 4; ++nf)
#pragma unroll
        for (int mi = 0; mi < 4; ++mi)
          acc1[mi][nf] = MFMA16(bw1[nf][kk], af[kk][mi], acc1[mi][nf]);
#pragma unroll
    for (int mi = 0; mi < 4; ++mi)
#pragma unroll
      for (int nf = 0; nf < 4; ++nf) {
        bf16x4 hv;
#pragma unroll
        for (int r = 0; r < 4; ++r) hv[r] = (__bf16)fmaxf(acc1[mi][nf][r], 0.f);
        *(bf16x4*)&H[mi * 16 + llo][wid * 64 + nf * 16 + lhi * 4] = hv;
      }
    __syncthreads();  // B2: H ready; A[cur^1] readers (2 barriers ago) done

    // ---- write prefetched next tile into A[cur^1] ----
    if (hn) {
#pragma unroll
      for (int s = 0; s < 4; ++s) {
        bf16x4 hv;
        hv[0] = (__bf16)pf[s].x; hv[1] = (__bf16)pf[s].y;
        hv[2] = (__bf16)pf[s].z; hv[3] = (__bf16)pf[s].w;
        *(bf16x4*)&A[cur ^ 1][srow[s]][sc4 * 4] = hv;
      }
    }

    // ---- layer 2: [64x256] @ [256x256], relu, column sums ----
    f32x4 acc2[4][4];
#pragma unroll
    for (int mi = 0; mi < 4; ++mi)
#pragma unroll
      for (int nf = 0; nf < 4; ++nf) acc2[mi][nf] = (f32x4){0.f, 0.f, 0.f, 0.f};
#pragma unroll
    for (int kk = 0; kk < 8; ++kk) {
      bf16x8 a2[4];
#pragma unroll
      for (int mi = 0; mi < 4; ++mi)
        a2[mi] = *(const bf16x8*)&H[mi * 16 + llo][kk * 32 + lhi * 8];
#pragma unroll
      for (int nf = 0; nf < 4; ++nf) {
        bf16x8 bf_ = *(const bf16x8*)(We1T +
                        (size_t)(wid * 64 + nf * 16 + llo) * 256 +
                        kk * 32 + lhi * 8);
#pragma unroll
        for (int mi = 0; mi < 4; ++mi)
          acc2[mi][nf] = MFMA16(a2[mi], bf_, acc2[mi][nf]);
      }
    }
    float colsum[4];
#pragma unroll
    for (int nf = 0; nf < 4; ++nf) colsum[nf] = 0.f;
#pragma unroll
    for (int mi = 0; mi < 4; ++mi)
#pragma unroll
      for (int nf = 0; nf < 4; ++nf)
#pragma unroll
        for (int r = 0; r < 4; ++r)
          colsum[nf] += fmaxf(acc2[mi][nf][r], 0.f);

    // reduce across lane-groups; write this item's partial pooled slice
    float* outp = part + (size_t)cit * 256;
#pragma unroll
    for (int nf = 0; nf < 4; ++nf) {
      float s = colsum[nf];
      s += __shfl_xor(s, 16);
      s += __shfl_xor(s, 32);
      if (lane < 16) outp[wid * 64 + nf * 16 + lane] = s;
    }

    cit = nit;
    cur ^= 1;
  }
}

// ---------------------------------------------------------------------------
// K3: head.  pooled = sum_{t<ceil(n/64)} part[b*8+t]; req_embed = relu(pooled
// @ W_e2); x = [x_inst, req_embed]; h = relu(x @ W_c + b_c); out = h@W_o+b_o.
// 16 batch rows per block, 128 blocks x 256 threads, fp32.
// ---------------------------------------------------------------------------
__global__ __launch_bounds__(256) void head_kernel(const float* __restrict__ x_inst,
                                                   const float* __restrict__ part,
                                                   const int* __restrict__ n_req,
                                                   const float* __restrict__ We2,
                                                   const float* __restrict__ Wc,
                                                   const float* __restrict__ bc,
                                                   const float* __restrict__ Wo,
                                                   const float* __restrict__ bo,
                                                   float* __restrict__ out) {
  __shared__ float P[16][256];
  __shared__ float XC[16][192];
  __shared__ float RED[4][16];
  const int tid = threadIdx.x;
  const int r0 = blockIdx.x * 16;

  // stage pooled rows (16x256) = sum of valid partials; x_inst -> XC[:,0:64]
#pragma unroll
  for (int i = 0; i < 4; ++i) {
    int flat = tid + i * 256;
    int row = flat >> 6, c4 = flat & 63;
    int ntiles = (n_req[r0 + row] + 63) >> 6;
    float4 s = make_float4(0.f, 0.f, 0.f, 0.f);
    for (int tt = 0; tt < ntiles; ++tt) {
      float4 p = ((const float4*)(part + ((size_t)(r0 + row) * 8 + tt) * 256))[c4];
      s.x += p.x; s.y += p.y; s.z += p.z; s.w += p.w;
    }
    *(float4*)&P[row][c4 * 4] = s;
  }
  {
    int row = tid >> 4, c4 = tid & 15;
    float4 w = ((const float4*)(x_inst + (size_t)(r0 + row) * 64))[c4];
    *(float4*)&XC[row][c4 * 4] = w;
  }
  __syncthreads();

  // req_embed: 128 cols, threads split {row-half rh, col j}
  {
    const int rh = tid >> 7, j = tid & 127;
    float acc[8] = {0.f, 0.f, 0.f, 0.f, 0.f, 0.f, 0.f, 0.f};
    for (int k4 = 0; k4 < 64; ++k4) {
      float w0 = We2[(k4 * 4 + 0) * 128 + j];
      float w1 = We2[(k4 * 4 + 1) * 128 + j];
      float w2 = We2[(k4 * 4 + 2) * 128 + j];
      float w3 = We2[(k4 * 4 + 3) * 128 + j];
#pragma unroll
      for (int rr = 0; rr < 8; ++rr) {
        float4 pv = *(const float4*)&P[rh * 8 + rr][k4 * 4];
        acc[rr] += pv.x * w0 + pv.y * w1 + pv.z * w2 + pv.w * w3;
      }
    }
#pragma unroll
    for (int rr = 0; rr < 8; ++rr)
      XC[rh * 8 + rr][64 + j] = fmaxf(acc[rr], 0.f);
  }
  __syncthreads();

  // hidden (192->512) + output dot, 2 cols per thread
  float part_r[16];
#pragma unroll
  for (int r = 0; r < 16; ++r) part_r[r] = 0.f;
#pragma unroll
  for (int jj = 0; jj < 2; ++jj) {
    const int j = tid + jj * 256;
    float acc[16];
#pragma unroll
    for (int r = 0; r < 16; ++r) acc[r] = 0.f;
    for (int k4 = 0; k4 < 48; ++k4) {
      float w0 = Wc[(k4 * 4 + 0) * 512 + j];
      float w1 = Wc[(k4 * 4 + 1) * 512 + j];
      float w2 = Wc[(k4 * 4 + 2) * 512 + j];
      float w3 = Wc[(k4 * 4 + 3) * 512 + j];
#pragma unroll
      for (int r = 0; r < 16; ++r) {
        float4 xv = *(const float4*)&XC[r][k4 * 4];
        acc[r] += xv.x * w0 + xv.y * w1 + xv.z * w2 + xv.w * w3;
      }
    }
    const float bcv = bc[j], wov = Wo[j];
#pragma unroll
    for (int r = 0; r < 16; ++r)
      part_r[r] += fmaxf(acc[r] + bcv, 0.f) * wov;
  }
  // block reduction of part_r[16] over 256 threads
#pragma unroll
  for (int r = 0; r < 16; ++r) {
    part_r[r] += __shfl_xor(part_r[r], 1);
    part_r[r] += __shfl_xor(part_r[r], 2);
    part_r[r] += __shfl_xor(part_r[r], 4);
    part_r[r] += __shfl_xor(part_r[r], 8);
    part_r[r] += __shfl_xor(part_r[r], 16);
    part_r[r] += __shfl_xor(part_r[r], 32);
  }
  const int wv = tid >> 6, lane = tid & 63;
  if (lane == 0) {
#pragma unroll
    for (int r = 0; r < 16; ++r) RED[wv][r] = part_r[r];
  }
  __syncthreads();
  if (tid < 16)
    out[r0 + tid] = RED[0][tid] + RED[1][tid] + RED[2][tid] + RED[3][tid] + bo[0];
}

// ---------------------------------------------------------------------------
extern "C" void kernel_launch(void* const* d_in, const int* in_sizes, int n_in,
                              void* d_out, int out_size, void* d_ws, size_t ws_size,
                              hipStream_t stream) {
  const float* x_inst = (const float*)d_in[0];
  const float* x_req  = (const float*)d_in[1];
  const int*   n_req  = (const int*)d_in[2];
  const float* W_in   = (const float*)d_in[3];
  const float* W_e1   = (const float*)d_in[4];
  const float* W_e2   = (const float*)d_in[5];
  const float* W_c    = (const float*)d_in[6];
  const float* b_c    = (const float*)d_in[7];
  const float* W_o    = (const float*)d_in[8];
  const float* b_o    = (const float*)d_in[9];
  float* out = (float*)d_out;

  char* ws = (char*)d_ws;
  const size_t PART_BYTES = (size_t)2048 * 8 * 256 * 4;        // 16.78 MB
  float*        partbuf  = (float*)ws;
  __bf16*       WinT     = (__bf16*)(ws + PART_BYTES);         // 32 KiB
  __bf16*       We1T     = (__bf16*)(ws + PART_BYTES + (32 << 10));   // 128 KiB
  unsigned int* worklist = (unsigned int*)(ws + PART_BYTES + (160 << 10));  // 64 KiB
  int*          wl_count = (int*)(ws + PART_BYTES + (224 << 10));

  prep<<<321, 256, 0, stream>>>(W_in, W_e1, n_req, WinT, We1T, worklist, wl_count);
  mlp_pool<<<G_BLOCKS, 256, 0, stream>>>(x_req, n_req, WinT, We1T, worklist,
                                         wl_count, partbuf);
  head_kernel<<<128, 256, 0, stream>>>(x_inst, partbuf, n_req, W_e2, W_c, b_c,
                                       W_o, b_o, out);
}